// Round 3
// baseline (790.568 us; speedup 1.0000x reference)
//
#include <hip/hip_runtime.h>

#define NV   1000000
#define NE   16000000
#define NXCD 8

// Native clang vector types (required by __builtin_nontemporal_load).
typedef int   vint4   __attribute__((ext_vector_type(4)));
typedef float vfloat4 __attribute__((ext_vector_type(4)));

// Which XCD (chiplet) is this wave running on? 0..7 on MI355X.
__device__ __forceinline__ unsigned xcc_id() {
    unsigned x;
    asm volatile("s_getreg_b32 %0, hwreg(HW_REG_XCC_ID)" : "=s"(x));
    return x & (NXCD - 1);
}

// Per-XCD privatized scatter: each XCD's blocks accumulate into their own
// 4 MB copy with WORKGROUP-scope atomics -> RMW executes in the local TCC/L2
// (no cross-XCD memory-side round trip). Edge streams use non-temporal loads
// so they don't evict the L2-resident accumulator.
__global__ void edge_scatter_priv(const vint4* __restrict__ src4,
                                  const vfloat4* __restrict__ ea4,
                                  float* __restrict__ accs, int ne4) {
    float* acc = accs + (size_t)xcc_id() * NV;
    int i = blockIdx.x * blockDim.x + threadIdx.x;
    int stride = gridDim.x * blockDim.x;
    for (; i < ne4; i += stride) {
        vint4 s = __builtin_nontemporal_load(&src4[i]);
        vfloat4 v = __builtin_nontemporal_load(&ea4[i]);
        __hip_atomic_fetch_add(&acc[s.x], v.x, __ATOMIC_RELAXED, __HIP_MEMORY_SCOPE_WORKGROUP);
        __hip_atomic_fetch_add(&acc[s.y], v.y, __ATOMIC_RELAXED, __HIP_MEMORY_SCOPE_WORKGROUP);
        __hip_atomic_fetch_add(&acc[s.z], v.z, __ATOMIC_RELAXED, __HIP_MEMORY_SCOPE_WORKGROUP);
        __hip_atomic_fetch_add(&acc[s.w], v.w, __ATOMIC_RELAXED, __HIP_MEMORY_SCOPE_WORKGROUP);
    }
}

// Fallback: single copy, device-scope atomics (correct anywhere).
__global__ void edge_scatter4(const vint4* __restrict__ src4,
                              const vfloat4* __restrict__ ea4,
                              float* __restrict__ acc, int ne4) {
    int i = blockIdx.x * blockDim.x + threadIdx.x;
    int stride = gridDim.x * blockDim.x;
    for (; i < ne4; i += stride) {
        vint4 s = src4[i];
        vfloat4 v = ea4[i];
        atomicAdd(&acc[s.x], v.x);
        atomicAdd(&acc[s.y], v.y);
        atomicAdd(&acc[s.z], v.z);
        atomicAdd(&acc[s.w], v.w);
    }
}

// Reduce the NXCD private copies and fuse the epilogue:
// out[i] = [A_ii, C_i, (sum_x acc[x][i]) / A_ii], row-major (N,3).
__global__ void vertex_out_priv(const float2* __restrict__ va,
                                const float* __restrict__ accs,
                                float* __restrict__ out, int nv) {
    int i = blockIdx.x * blockDim.x + threadIdx.x;
    if (i < nv) {
        float g = 0.f;
        #pragma unroll
        for (int x = 0; x < NXCD; ++x)
            g += accs[(size_t)x * NV + i];
        float2 v = va[i];
        out[3 * i + 0] = v.x;
        out[3 * i + 1] = v.y;
        out[3 * i + 2] = g / v.x;
    }
}

__global__ void vertex_out(const float2* __restrict__ va,
                           const float* __restrict__ acc,
                           float* __restrict__ out, int nv) {
    int i = blockIdx.x * blockDim.x + threadIdx.x;
    if (i < nv) {
        float2 v = va[i];
        float g = acc[i];
        out[3 * i + 0] = v.x;
        out[3 * i + 1] = v.y;
        out[3 * i + 2] = g / v.x;
    }
}

extern "C" void kernel_launch(void* const* d_in, const int* in_sizes, int n_in,
                              void* d_out, int out_size, void* d_ws, size_t ws_size,
                              hipStream_t stream) {
    const float* vertex_attr = (const float*)d_in[0];   // (NV, 2) f32
    const int*   edgeij      = (const int*)d_in[1];     // (2, NE) int32; row 0 = src
    const float* edge_attr   = (const float*)d_in[2];   // (NE, 1) f32
    float* out = (float*)d_out;                          // (NV, 3) f32
    float* acc = (float*)d_ws;

    int ne4 = NE / 4;
    int blocks = 2048;
    int vblocks = (NV + 255) / 256;

    size_t priv_bytes = (size_t)NXCD * NV * sizeof(float);
    if (ws_size >= priv_bytes) {
        // Zero all 8 private copies every call (harness does not re-poison d_ws).
        (void)hipMemsetAsync(acc, 0, priv_bytes, stream);
        edge_scatter_priv<<<blocks, 256, 0, stream>>>(
            (const vint4*)edgeij, (const vfloat4*)edge_attr, acc, ne4);
        vertex_out_priv<<<vblocks, 256, 0, stream>>>(
            (const float2*)vertex_attr, acc, out, NV);
    } else {
        (void)hipMemsetAsync(acc, 0, (size_t)NV * sizeof(float), stream);
        edge_scatter4<<<blocks, 256, 0, stream>>>(
            (const vint4*)edgeij, (const vfloat4*)edge_attr, acc, ne4);
        vertex_out<<<vblocks, 256, 0, stream>>>(
            (const float2*)vertex_attr, acc, out, NV);
    }
}